// Round 1
// baseline (25955.933 us; speedup 1.0000x reference)
//
#include <hip/hip_runtime.h>
#include <cstddef>

#define HID  256
#define CTXD 128
#define QD   128
#define VD   33

__device__ __forceinline__ float sigf(float x) { return 1.f / (1.f + expf(-x)); }

// ---------------------------------------------------------------------------
// LSTM layer kernel. grid = 256 blocks (one per hidden unit j), 256 threads:
// thread = which*64 + b  (which = gate i/f/g/o, b = batch lane).
// Layouts: hT/cT/ctxT are transposed [k][b] (b contiguous -> coalesced lanes).
// hRead = this layer's h from previous step; hWrite = new h (ping-pong buffer,
// required because every block reads ALL k of hRead while writing its own j).
// ---------------------------------------------------------------------------
template<bool FIRST>
__global__ __launch_bounds__(256) void lstm_kernel(
    const float* __restrict__ Wih, const float* __restrict__ Whh,
    const float* __restrict__ bih, const float* __restrict__ bhh,
    const float* __restrict__ embed, const int* __restrict__ chr,
    const float* __restrict__ ctxT,   // FIRST only
    const float* __restrict__ xT,     // !FIRST: previous layer's NEW h, [256][64]
    const float* __restrict__ hRead,  // own layer prev-step h, [256][64]
    float* __restrict__ hWrite,       // own layer new h
    float* __restrict__ cT)           // own layer cell state (in-place safe)
{
    const int j     = blockIdx.x;
    const int tid   = threadIdx.x;
    const int which = tid >> 6;
    const int b     = tid & 63;
    const int row   = which * HID + j;        // torch LSTMCell gate order i,f,g,o
    const int XDIM  = FIRST ? (HID + CTXD) : HID;

    const float* wi = Wih + (size_t)row * XDIM;
    const float* wh = Whh + (size_t)row * HID;
    float acc = bih[row] + bhh[row];

    if (FIRST) {
        const float* emb = embed + chr[b] * HID;   // x = [embed[char], ctx]
        #pragma unroll 8
        for (int k = 0; k < HID; ++k)  acc += emb[k] * wi[k];
        #pragma unroll 8
        for (int k = 0; k < CTXD; ++k) acc += ctxT[k * 64 + b] * wi[HID + k];
    } else {
        #pragma unroll 8
        for (int k = 0; k < HID; ++k)  acc += xT[k * 64 + b] * wi[k];
    }
    #pragma unroll 8
    for (int k = 0; k < HID; ++k)      acc += hRead[k * 64 + b] * wh[k];

    __shared__ float g[4][64];
    g[which][b] = acc;
    __syncthreads();

    if (tid < 64) {
        float gi = g[0][tid], gf = g[1][tid], gg = g[2][tid], go = g[3][tid];
        float cold = cT[j * 64 + tid];
        float cnew = sigf(gf) * cold + sigf(gi) * tanhf(gg);
        cT[j * 64 + tid]     = cnew;
        hWrite[j * 64 + tid] = sigf(go) * tanhf(cnew);
    }
}

// ---------------------------------------------------------------------------
// Fused per-batch attention + MLP + argmax. One block per batch element,
// 512 threads. Phases: query -> energy (float4 over t) -> softmax (global max
// like reference, then mask, then renormalize with 1e-12 floor) -> scores out
// -> ctx (loop bounded at seq_size; masked scores are 0) -> MLP -> predict out
// -> greedy argmax feedback.
// ---------------------------------------------------------------------------
__global__ __launch_bounds__(512) void attn_kernel(
    const float* __restrict__ key,   // [B][128][T]
    const float* __restrict__ val,   // [B][T][128]
    const int*   __restrict__ seqs,
    const float* __restrict__ h2T,   // layer-2 new h, [256][64]
    const float* __restrict__ Wq,  const float* __restrict__ bq,
    const float* __restrict__ Ws1, const float* __restrict__ bs1,
    const float* __restrict__ Ws2, const float* __restrict__ bs2,
    float* __restrict__ ctxT, int* __restrict__ chr,
    float* __restrict__ scores_out,  // pre-offset by s*T; + b*sStrideB
    float* __restrict__ pred_out,    // pre-offset by s*V; + b*pStrideB
    size_t sStrideB, size_t pStrideB, int T)
{
    extern __shared__ float s_lds[];          // T floats: energy -> p -> score
    __shared__ float  qry[QD];
    __shared__ float4 red[16][32];
    __shared__ float  ctx_lds[CTXD];
    __shared__ float  hid[HID];
    __shared__ float  predv[VD];
    __shared__ float  wred[8];
    __shared__ float  bc;

    const int b   = blockIdx.x;
    const int tid = threadIdx.x;
    const int T4  = T >> 2;

    // --- query = h2 @ Wq^T + bq ---
    if (tid < QD) {
        float a = bq[tid];
        const float* wq = Wq + tid * HID;
        #pragma unroll 8
        for (int k = 0; k < HID; ++k) a += h2T[k * 64 + b] * wq[k];  // broadcast reads
        qry[tid] = a;
    }
    __syncthreads();

    // --- energy[t] = sum_q qry[q] * key[b][q][t] ---
    const float4* key4 = (const float4*)key + (size_t)b * QD * T4;
    for (int t4 = tid; t4 < T4; t4 += 512) {
        float4 e = make_float4(0.f, 0.f, 0.f, 0.f);
        #pragma unroll 4
        for (int q = 0; q < QD; ++q) {
            float4 k4 = key4[(size_t)q * T4 + t4];
            float  qv = qry[q];
            e.x += qv * k4.x; e.y += qv * k4.y; e.z += qv * k4.z; e.w += qv * k4.w;
        }
        ((float4*)s_lds)[t4] = e;
    }
    __syncthreads();

    // --- softmax over ALL t (matches reference: softmax, then mask, then renorm) ---
    float m = -INFINITY;
    for (int t = tid; t < T; t += 512) m = fmaxf(m, s_lds[t]);
    #pragma unroll
    for (int off = 32; off; off >>= 1) m = fmaxf(m, __shfl_xor(m, off));
    if ((tid & 63) == 0) wred[tid >> 6] = m;
    __syncthreads();
    if (tid == 0) { float r = wred[0]; for (int i = 1; i < 8; ++i) r = fmaxf(r, wred[i]); bc = r; }
    __syncthreads();
    m = bc;

    float zs = 0.f;
    for (int t = tid; t < T; t += 512) { float p = expf(s_lds[t] - m); s_lds[t] = p; zs += p; }
    #pragma unroll
    for (int off = 32; off; off >>= 1) zs += __shfl_xor(zs, off);
    __syncthreads();
    if ((tid & 63) == 0) wred[tid >> 6] = zs;
    __syncthreads();
    if (tid == 0) { float r = 0.f; for (int i = 0; i < 8; ++i) r += wred[i]; bc = r; }
    __syncthreads();
    const float Z = bc;

    const int n = seqs[b];
    float ms = 0.f;
    for (int t = tid; t < T; t += 512) {
        float sc = s_lds[t] / Z;
        sc = (t < n) ? sc : 0.f;
        s_lds[t] = sc;
        ms += sc;
    }
    #pragma unroll
    for (int off = 32; off; off >>= 1) ms += __shfl_xor(ms, off);
    __syncthreads();
    if ((tid & 63) == 0) wred[tid >> 6] = ms;
    __syncthreads();
    if (tid == 0) { float r = 0.f; for (int i = 0; i < 8; ++i) r += wred[i]; bc = r; }
    __syncthreads();
    const float denom = fmaxf(bc, 1e-12f);

    float* so = scores_out + (size_t)b * sStrideB;
    for (int t = tid; t < T; t += 512) {
        float sc = s_lds[t] / denom;
        s_lds[t] = sc;
        so[t]    = sc;
    }
    __syncthreads();

    // --- ctx[c] = sum_t score[t] * val[b][t][c]  (t >= n contributes 0) ---
    const int c4 = tid & 31, grp = tid >> 5;     // 32 float4-columns x 16 t-groups
    const float4* val4 = (const float4*)val + (size_t)b * T * 32;
    float4 a4 = make_float4(0.f, 0.f, 0.f, 0.f);
    #pragma unroll 4
    for (int t = grp; t < n; t += 16) {
        float  sv = s_lds[t];
        float4 v4 = val4[(size_t)t * 32 + c4];
        a4.x += sv * v4.x; a4.y += sv * v4.y; a4.z += sv * v4.z; a4.w += sv * v4.w;
    }
    red[grp][c4] = a4;
    __syncthreads();
    if (tid < 32) {
        float4 r = red[0][tid];
        for (int g2 = 1; g2 < 16; ++g2) {
            float4 q = red[g2][tid];
            r.x += q.x; r.y += q.y; r.z += q.z; r.w += q.w;
        }
        const int c0 = tid * 4;
        ctx_lds[c0 + 0] = r.x; ctx_lds[c0 + 1] = r.y;
        ctx_lds[c0 + 2] = r.z; ctx_lds[c0 + 3] = r.w;
        ctxT[(c0 + 0) * 64 + b] = r.x;
        ctxT[(c0 + 1) * 64 + b] = r.y;
        ctxT[(c0 + 2) * 64 + b] = r.z;
        ctxT[(c0 + 3) * 64 + b] = r.w;
    }
    __syncthreads();

    // --- MLP: hid = relu([h2, ctx] @ Ws1^T + bs1); predict = hid @ Ws2^T + bs2 ---
    if (tid < HID) {
        float a = bs1[tid];
        const float* w1 = Ws1 + tid * (HID + CTXD);
        #pragma unroll 8
        for (int k = 0; k < HID; ++k)  a += h2T[k * 64 + b] * w1[k];
        #pragma unroll 8
        for (int k = 0; k < CTXD; ++k) a += ctx_lds[k] * w1[HID + k];
        hid[tid] = fmaxf(a, 0.f);
    }
    __syncthreads();
    if (tid < VD) {
        float a = bs2[tid];
        const float* w2 = Ws2 + tid * HID;
        #pragma unroll 8
        for (int k = 0; k < HID; ++k) a += hid[k] * w2[k];
        pred_out[(size_t)b * pStrideB + tid] = a;
        predv[tid] = a;
    }
    __syncthreads();
    if (tid == 0) {   // jnp.argmax: first occurrence of max -> strict >
        int best = 0; float bv = predv[0];
        for (int v = 1; v < VD; ++v) if (predv[v] > bv) { bv = predv[v]; best = v; }
        chr[b] = best;
    }
}

// ---------------------------------------------------------------------------
// Initialize state in d_ws (poisoned 0xAA by harness; must re-init every call).
// ---------------------------------------------------------------------------
__global__ void init_kernel(float* hA, float* cT, float* ctxT, int* chr,
                            const float* h0, const float* c0, const float* con)
{
    int i = blockIdx.x * 256 + threadIdx.x;
    if (i < 3 * HID * 64) {
        int lk = i >> 6;           // l*256 + k
        hA[i] = h0[lk];
        cT[i] = c0[lk];
    }
    if (i < CTXD * 64) ctxT[i] = con[i >> 6];
    if (i < 64)        chr[i]  = 0;
}

extern "C" void kernel_launch(void* const* d_in, const int* in_sizes, int n_in,
                              void* d_out, int out_size, void* d_ws, size_t ws_size,
                              hipStream_t stream)
{
    const int*   seqs  = (const int*)  d_in[0];
    const float* key   = (const float*)d_in[1];
    const float* val   = (const float*)d_in[2];
    // d_in[3] = labels: only its size (S) is used
    const float* embed = (const float*)d_in[4];
    const float* Wih0  = (const float*)d_in[5];
    const float* Whh0  = (const float*)d_in[6];
    const float* bih0  = (const float*)d_in[7];
    const float* bhh0  = (const float*)d_in[8];
    const float* Wih1  = (const float*)d_in[9];
    const float* Whh1  = (const float*)d_in[10];
    const float* bih1  = (const float*)d_in[11];
    const float* bhh1  = (const float*)d_in[12];
    const float* Wih2  = (const float*)d_in[13];
    const float* Whh2  = (const float*)d_in[14];
    const float* bih2  = (const float*)d_in[15];
    const float* bhh2  = (const float*)d_in[16];
    const float* Wq    = (const float*)d_in[17];
    const float* bq    = (const float*)d_in[18];
    const float* Ws1   = (const float*)d_in[19];
    const float* bs1   = (const float*)d_in[20];
    const float* Ws2   = (const float*)d_in[21];
    const float* bs2   = (const float*)d_in[22];
    const float* h0    = (const float*)d_in[23];
    const float* c0    = (const float*)d_in[24];
    const float* con   = (const float*)d_in[25];

    const int B = in_sizes[0];                 // 64
    const int T = in_sizes[1] / (B * QD);      // 2048
    const int S = in_sizes[3] / B;             // 220

    // workspace layout (floats): hA | hB | cT | ctxT | chr
    float* ws = (float*)d_ws;
    const size_t HB = (size_t)3 * HID * 64;    // one h buffer (3 layers)
    float* hA   = ws;
    float* hB   = ws + HB;
    float* cT   = ws + 2 * HB;
    float* ctxT = ws + 3 * HB;
    int*   chr  = (int*)(ws + 3 * HB + (size_t)CTXD * 64);

    init_kernel<<<192, 256, 0, stream>>>(hA, cT, ctxT, chr, h0, c0, con);

    float* out = (float*)d_out;
    const size_t scoresTotal = (size_t)B * S * T;
    const size_t sStrideB    = (size_t)S * T;
    const size_t pStrideB    = (size_t)S * VD;

    for (int s = 0; s < S; ++s) {
        const int p  = s & 1;
        float* hR = p ? hB : hA;   // read  prev-step h
        float* hW = p ? hA : hB;   // write new h

        lstm_kernel<true ><<<HID, 256, 0, stream>>>(Wih0, Whh0, bih0, bhh0,
            embed, chr, ctxT, nullptr,
            hR, hW, cT);
        lstm_kernel<false><<<HID, 256, 0, stream>>>(Wih1, Whh1, bih1, bhh1,
            nullptr, nullptr, nullptr, hW,
            hR + HID * 64, hW + HID * 64, cT + HID * 64);
        lstm_kernel<false><<<HID, 256, 0, stream>>>(Wih2, Whh2, bih2, bhh2,
            nullptr, nullptr, nullptr, hW + HID * 64,
            hR + 2 * HID * 64, hW + 2 * HID * 64, cT + 2 * HID * 64);

        attn_kernel<<<B, 512, T * sizeof(float), stream>>>(key, val, seqs,
            hW + 2 * HID * 64,
            Wq, bq, Ws1, bs1, Ws2, bs2, ctxT, chr,
            out + (size_t)s * T, out + scoresTotal + (size_t)s * VD,
            sStrideB, pStrideB, T);
    }
}